// Round 4
// baseline (466.547 us; speedup 1.0000x reference)
//
#include <hip/hip_runtime.h>
#include <hip/hip_bf16.h>
#include <math.h>

// GAT 2-layer fused pipeline for MI355X (gfx950).
// Round-13: degree-bucketed node permutation for gat_agg load balance.
// r12 post-mortem: gat loop iterations = ceil(wave-max-degree/4); degree
// ~Poisson(16) => E[max of 4 nodes] ~ 20 vs mean 16 => ~30% idle edge
// slots. Fix: counting-sort nodes by exact degree (64 buckets x 8
// contention sub-buckets) into perm[]; gat waves process perm order so
// all 4 nodes per wave share one degree. Count rides on finalize (degrees
// already in LDS); +1 tiny scan kernel +1 scatter kernel. Per-node math,
// edge order, and output addressing unchanged -> bitwise-identical output.
// GEMM (64-row single-pass-A) and CSR build unchanged from r12.

#define SLOPE 0.2f

typedef __attribute__((ext_vector_type(8))) __bf16 bf16x8;
typedef __attribute__((ext_vector_type(4))) float f32x4;

__device__ __forceinline__ float gelu_erf(float x) {
    return 0.5f * x * (1.0f + erff(x * 0.70710678118654752f));
}

__device__ __forceinline__ unsigned short f2bf(float f) {  // RNE
    unsigned int u = __float_as_uint(f);
    return (unsigned short)((u + 0x7fffu + ((u >> 16) & 1u)) >> 16);
}
__device__ __forceinline__ float bf2f(unsigned short h) {
    return __uint_as_float((unsigned int)h << 16);
}

// 16-lane (row) all-reduce sum via DPP row_ror 1,2,4,8; every lane of the
// row ends with the row's sum. Chains over different inputs are independent.
__device__ __forceinline__ float row16_sum(float x) {
    x += __int_as_float(__builtin_amdgcn_update_dpp(0, __float_as_int(x), 0x121, 0xF, 0xF, true));
    x += __int_as_float(__builtin_amdgcn_update_dpp(0, __float_as_int(x), 0x122, 0xF, 0xF, true));
    x += __int_as_float(__builtin_amdgcn_update_dpp(0, __float_as_int(x), 0x124, 0xF, 0xF, true));
    x += __int_as_float(__builtin_amdgcn_update_dpp(0, __float_as_int(x), 0x128, 0xF, 0xF, true));
    return x;
}

// XOR swizzle for LDS planes with 256B row stride: spreads the 16-row
// column slice of a ds_read_b128 across 8 distinct 16B slots.
__device__ __forceinline__ int swz(int off) { return off ^ ((off >> 4) & 0x70); }

// ---------------- weight prepack ---------------------------------------------
// Pack index i = ((ct*4+ks)*64 + lane)*8 + j  ->  W[k][n],
// k = ks*32 + (lane>>4)*8 + j,  n = ct*16 + (lane&15).  hi at [i], lo at [CE+i].
__global__ __launch_bounds__(256) void pack_w(
    const float* __restrict__ W0,  const float* __restrict__ Wq1,
    const float* __restrict__ Wp1, const float* __restrict__ Wq2,
    const float* __restrict__ Wp2,
    unsigned short* __restrict__ P0,  unsigned short* __restrict__ Pq1,
    unsigned short* __restrict__ Pp1, unsigned short* __restrict__ Pq2,
    unsigned short* __restrict__ Pp2)
{
    const float* W; unsigned short* P; int C;
    switch (blockIdx.y) {
        case 0:  W = W0;  P = P0;  C = 128; break;
        case 1:  W = Wq1; P = Pq1; C = 128; break;
        case 2:  W = Wp1; P = Pp1; C = 128; break;
        case 3:  W = Wq2; P = Pq2; C = 64;  break;
        default: W = Wp2; P = Pp2; C = 64;  break;
    }
    int i = blockIdx.x * 256 + threadIdx.x;
    int CE = C * 128;
    if (i >= CE) return;
    int j = i & 7, l = (i >> 3) & 63, ks = (i >> 9) & 3, ct = i >> 11;
    int k = ks * 32 + ((l >> 4) << 3) + j;
    int n = ct * 16 + (l & 15);
    float v = W[k * C + n];
    unsigned short hb = f2bf(v);
    P[i] = hb;
    P[CE + i] = f2bf(v - bf2f(hb));
}

// ---------------- MFMA GEMM -------------------------------------------------
// Block = 64 rows x ALL output cols; 4 waves split the col-tiles.
// A panel (64x128, hi+lo bf16 = 32 KB) staged in LDS once (swizzled);
// W fragments streamed from packed global (L2-resident).
// EPI 0: single matrix, out = gelu -> o1hi/o1lo (layer 0, A = fp32).
// EPI 1: TWO matrices: waves 0-1 -> q fp32 (direct), waves 2-3 -> p bf16
//        (LDS-bounced for coalesced 16B stores).
template <int C, bool TWO, int EPI>
__global__ __launch_bounds__(256) void mfma_gemm(
    const float* __restrict__ Af,
    const unsigned short* __restrict__ AHg, const unsigned short* __restrict__ ALg,
    const unsigned short* __restrict__ P1, const float* __restrict__ b1,
    const unsigned short* __restrict__ P2, const float* __restrict__ b2,
    float* __restrict__ outq, unsigned short* __restrict__ outp,
    unsigned short* __restrict__ o1hi, unsigned short* __restrict__ o1lo,
    int N)
{
    constexpr int CE  = C * 128;
    constexpr int CTT = (TWO ? 2 : 1) * (C / 16);   // total col-tiles
    constexpr int CTW = CTT / 4;                    // tiles per wave
    constexpr int QCT = C / 16;                     // tiles in first matrix

    __shared__ __align__(16) unsigned char lds[32768]; // hi plane [0,16K), lo [16K,32K)

    const int t = threadIdx.x;
    const int lane = t & 63;
    const int w = t >> 6;
    const int row0 = blockIdx.x * 64;
    const int mcol = lane & 15;
    const int hk = lane >> 4;

    // ---- stage A (64 rows x 128 dims) as hi/lo bf16 into LDS ----
    if constexpr (EPI == 0) {
#pragma unroll
        for (int i = 0; i < 8; i++) {
            int idx = t + i * 256;            // float4 index, 2048 total
            int row = idx >> 5;               // 32 float4 per row
            int gr = row0 + row;
            float4 v = make_float4(0.f, 0.f, 0.f, 0.f);
            if (gr < N) v = *reinterpret_cast<const float4*>(Af + (size_t)gr * 128 + (idx & 31) * 4);
            const float* f = reinterpret_cast<const float*>(&v);
            unsigned int h[4], l[4];
#pragma unroll
            for (int j = 0; j < 4; j++) {
                unsigned short hb = f2bf(f[j]);
                h[j] = hb;
                l[j] = f2bf(f[j] - bf2f(hb));
            }
            int so = swz(row * 256 + (idx & 31) * 8);
            *reinterpret_cast<uint2*>(&lds[so])         = make_uint2(h[0] | (h[1] << 16), h[2] | (h[3] << 16));
            *reinterpret_cast<uint2*>(&lds[16384 + so]) = make_uint2(l[0] | (l[1] << 16), l[2] | (l[3] << 16));
        }
    } else {
#pragma unroll
        for (int i = 0; i < 4; i++) {
            int idx = t + i * 256;            // uint4 index, 1024 per plane
            int row = idx >> 4;               // 16 uint4 per row
            int gr = row0 + row;
            uint4 vh = make_uint4(0, 0, 0, 0), vl = make_uint4(0, 0, 0, 0);
            if (gr < N) {
                vh = *reinterpret_cast<const uint4*>(AHg + (size_t)gr * 128 + (idx & 15) * 8);
                vl = *reinterpret_cast<const uint4*>(ALg + (size_t)gr * 128 + (idx & 15) * 8);
            }
            int so = swz(row * 256 + (idx & 15) * 16);
            *reinterpret_cast<uint4*>(&lds[so])         = vh;
            *reinterpret_cast<uint4*>(&lds[16384 + so]) = vl;
        }
    }
    __syncthreads();

    f32x4 acc[CTW][4];
#pragma unroll
    for (int c = 0; c < CTW; c++)
#pragma unroll
        for (int rf = 0; rf < 4; rf++) acc[c][rf] = (f32x4){0.f, 0.f, 0.f, 0.f};

#pragma unroll
    for (int ks = 0; ks < 4; ks++) {
        bf16x8 ah[4], al[4];
#pragma unroll
        for (int rf = 0; rf < 4; rf++) {
            int so = swz((rf * 16 + mcol) * 256 + ks * 64 + hk * 16);
            ah[rf] = *reinterpret_cast<const bf16x8*>(&lds[so]);
            al[rf] = *reinterpret_cast<const bf16x8*>(&lds[16384 + so]);
        }
#pragma unroll
        for (int c = 0; c < CTW; c++) {
            int ctg = w * CTW + c;
            bool isq = (!TWO) || (ctg < QCT);
            int ct = isq ? ctg : ctg - QCT;
            const unsigned short* P = isq ? P1 : P2;
            const unsigned short* Wp = P + ((ct * 4 + ks) * 64 + lane) * 8;
            bf16x8 bh = *reinterpret_cast<const bf16x8*>(Wp);
            bf16x8 bl = *reinterpret_cast<const bf16x8*>(Wp + CE);
#pragma unroll
            for (int rf = 0; rf < 4; rf++) {
                acc[c][rf] = __builtin_amdgcn_mfma_f32_16x16x32_bf16(ah[rf], bh, acc[c][rf], 0, 0, 0);
                acc[c][rf] = __builtin_amdgcn_mfma_f32_16x16x32_bf16(al[rf], bh, acc[c][rf], 0, 0, 0);
                acc[c][rf] = __builtin_amdgcn_mfma_f32_16x16x32_bf16(ah[rf], bl, acc[c][rf], 0, 0, 0);
            }
        }
    }

    __syncthreads();   // all A ds_reads done; LDS reused for epilogue staging

    // epilogue: C/D layout col=lane&15, row=(lane>>4)*4+reg
    if constexpr (EPI == 0) {
#pragma unroll
        for (int c = 0; c < CTW; c++) {
            int col = (w * CTW + c) * 16 + mcol;
            float bv = b1[col];
#pragma unroll
            for (int rf = 0; rf < 4; rf++) {
#pragma unroll
                for (int r = 0; r < 4; r++) {
                    int row = rf * 16 + hk * 4 + r;
                    float v = gelu_erf(acc[c][rf][r] + bv);
                    unsigned short hb = f2bf(v);
                    int bo = row * 256 + col * 2;
                    *reinterpret_cast<unsigned short*>(&lds[swz(bo)])         = hb;
                    *reinterpret_cast<unsigned short*>(&lds[16384 + swz(bo)]) = f2bf(v - bf2f(hb));
                }
            }
        }
        __syncthreads();
#pragma unroll
        for (int i = 0; i < 8; i++) {
            int idx = t + i * 256;          // 2048 uint4: hi 0..1023, lo 1024..2047
            int pl = idx >> 10;
            int j = idx & 1023;
            int row = j >> 4;
            int gr = row0 + row;
            if (gr < N) {
                uint4 v = *reinterpret_cast<const uint4*>(&lds[pl * 16384 + swz(row * 256 + (j & 15) * 16)]);
                unsigned short* dp = pl ? o1lo : o1hi;
                *reinterpret_cast<uint4*>(dp + (size_t)gr * 128 + (j & 15) * 8) = v;
            }
        }
    } else {
#pragma unroll
        for (int c = 0; c < CTW; c++) {
            int ctg = w * CTW + c;
            bool isq = ctg < QCT;
            int ct = isq ? ctg : ctg - QCT;
            int col = ct * 16 + mcol;
            float bv = (isq ? b1 : b2)[col];
#pragma unroll
            for (int rf = 0; rf < 4; rf++) {
#pragma unroll
                for (int r = 0; r < 4; r++) {
                    int row = rf * 16 + hk * 4 + r;
                    int gr = row0 + row;
                    float v = acc[c][rf][r] + bv;
                    if (isq) {
                        if (gr < N) outq[(size_t)gr * C + col] = v;   // 4B x 16 lanes = full line
                    } else {
                        *reinterpret_cast<unsigned short*>(&lds[swz(row * 256 + col * 2)]) = f2bf(v);
                    }
                }
            }
        }
        __syncthreads();
        constexpr int SLOTS = C / 8;        // uint4 slots per row (16 or 8)
#pragma unroll
        for (int i = 0; i < (64 * SLOTS) / 256; i++) {
            int idx = t + i * 256;
            int row = idx / SLOTS;
            int sl = idx % SLOTS;
            int gr = row0 + row;
            if (gr < N)
                *reinterpret_cast<uint4*>(outp + (size_t)gr * C + sl * 8) =
                    *reinterpret_cast<const uint4*>(&lds[swz(row * 256 + sl * 16)]);
        }
    }
}

// ---------------- CSR build: atomic-free two-level counting sort -------------
// Coarse bin = dst >> 4 (16 nodes per bin), CB = ceil(N/16) <= 4096.
// 64 edge-blocks; gh[bin*64 + blk] = count (bin-major for linear scan).

__global__ __launch_bounds__(256) void hist_coarse(
    const int* __restrict__ dst, int* __restrict__ gh, int* __restrict__ dbkt,
    int E, int CB)
{
    __shared__ int cnt[4096];
    const int blk = blockIdx.x;     // 0..63
    const int t = threadIdx.x;
    if (blk == 0)                   // zero degree-bucket counters for r13 perm
        for (int b = t; b < 512; b += 256) dbkt[b] = 0;
    for (int b = t; b < CB; b += 256) cnt[b] = 0;
    __syncthreads();
    const int epb = (E + 63) / 64;
    const int s = blk * epb;
    const int e_ = (s + epb < E) ? s + epb : E;
    for (int i = s + t; i < e_; i += 256)
        atomicAdd(&cnt[dst[i] >> 4], 1);
    __syncthreads();
    for (int b = t; b < CB; b += 256)
        gh[b * 64 + blk] = cnt[b];
}

// hierarchical exclusive scan over M = CB*64 values: gh -> gscan
__global__ __launch_bounds__(256) void scan1_kernel(const int* __restrict__ gh,
                                                    int* __restrict__ gscan,
                                                    int* __restrict__ bsum, int M)
{
    __shared__ int lds[256];
    int t = threadIdx.x;
    int i = blockIdx.x * 256 + t;
    int v = (i < M) ? gh[i] : 0;
    lds[t] = v;
    __syncthreads();
    int x = v;
    for (int off = 1; off < 256; off <<= 1) {
        int y = (t >= off) ? lds[t - off] : 0;
        __syncthreads();
        x += y;
        lds[t] = x;
        __syncthreads();
    }
    if (i < M) gscan[i] = x - v;
    if (t == 255) bsum[blockIdx.x] = x;
}

__global__ __launch_bounds__(1024) void scan2_kernel(int* __restrict__ bsum, int NB)
{
    __shared__ int lds[1024];
    int t = threadIdx.x;
    int v = (t < NB) ? bsum[t] : 0;
    lds[t] = v;
    __syncthreads();
    int x = v;
    for (int off = 1; off < 1024; off <<= 1) {
        int y = (t >= off) ? lds[t - off] : 0;
        __syncthreads();
        x += y;
        lds[t] = x;
        __syncthreads();
    }
    if (t < NB) bsum[t] = x - v;
}

__global__ __launch_bounds__(256) void scan3_kernel(int* __restrict__ gscan,
                                                    const int* __restrict__ bsum, int M)
{
    int i = blockIdx.x * 256 + threadIdx.x;
    if (i < M) gscan[i] += bsum[blockIdx.x];
}

// scatter edges into coarse-bin-grouped (dst,src) pairs; LDS cursors only.
__global__ __launch_bounds__(256) void scatter_coarse(
    const int* __restrict__ src, const int* __restrict__ dst,
    const int* __restrict__ gscan, int2* __restrict__ pairs, int E, int CB)
{
    __shared__ int cur[4096];
    const int blk = blockIdx.x;     // 0..63
    const int t = threadIdx.x;
    for (int b = t; b < CB; b += 256)
        cur[b] = gscan[b * 64 + blk];
    __syncthreads();
    const int epb = (E + 63) / 64;
    const int s = blk * epb;
    const int e_ = (s + epb < E) ? s + epb : E;
    for (int i = s + t; i < e_; i += 256) {
        int d = dst[i];
        int sv = src[i];
        int pos = atomicAdd(&cur[d >> 4], 1);   // LDS atomic
        pairs[pos] = make_int2(d, sv);
    }
}

// one block per coarse bin: exact CSR within the bin's contiguous segment.
// Also counts node degrees into dbkt[min(deg,63)*8 + (c&7)] for the perm.
__global__ __launch_bounds__(256) void finalize_kernel(
    const int2* __restrict__ pairs, const int* __restrict__ gscan,
    int* __restrict__ offs, int* __restrict__ csr_src, int* __restrict__ dbkt,
    int N, int E, int CB)
{
    const int c = blockIdx.x;
    const int t = threadIdx.x;
    __shared__ unsigned int cnt[8], rnk[8];
    __shared__ int pref[16];
    if (t < 8) { cnt[t] = 0u; rnk[t] = 0u; }
    __syncthreads();

    const int s  = gscan[c * 64];
    const int e_ = (c + 1 < CB) ? gscan[(c + 1) * 64] : E;
    const int base = c * 16;

    for (int i = s + t; i < e_; i += 256) {
        int d = pairs[i].x - base;    // 0..15
        atomicAdd(&cnt[d >> 1], 1u << ((d & 1) * 16));
    }
    __syncthreads();
    if (t == 0) {
        int run = s;
        for (int j = 0; j < 16; j++) {
            pref[j] = run;
            run += (int)((cnt[j >> 1] >> ((j & 1) * 16)) & 0xffffu);
        }
    }
    __syncthreads();
    if (t < 16 && base + t < N) {
        offs[base + t] = pref[t];
        int deg = (int)((cnt[t >> 1] >> ((t & 1) * 16)) & 0xffffu);
        int b = ((deg < 63 ? deg : 63) << 3) | (c & 7);
        atomicAdd(&dbkt[b], 1);
    }
    if (c == CB - 1 && t == 0) offs[N] = E;

    for (int i = s + t; i < e_; i += 256) {
        int2 pr = pairs[i];
        int d = pr.x - base;
        unsigned int old = atomicAdd(&rnk[d >> 1], 1u << ((d & 1) * 16));
        int r = (int)((old >> ((d & 1) * 16)) & 0xffffu);
        csr_src[pref[d] + r] = pr.y;
    }
}

// exclusive scan (in place) over the 512 degree-bucket counters.
__global__ __launch_bounds__(512) void scan_dbkt(int* __restrict__ dbkt)
{
    __shared__ int lds[512];
    int t = threadIdx.x;
    int v = dbkt[t];
    lds[t] = v;
    __syncthreads();
    int x = v;
    for (int off = 1; off < 512; off <<= 1) {
        int y = (t >= off) ? lds[t - off] : 0;
        __syncthreads();
        x += y;
        lds[t] = x;
        __syncthreads();
    }
    dbkt[t] = x - v;
}

// scatter nodes into degree-sorted perm[] (consumes dbkt prefix cursors).
__global__ __launch_bounds__(256) void scatter_perm(
    const int* __restrict__ offs, int* __restrict__ dbkt,
    int* __restrict__ perm, int N)
{
    int n = blockIdx.x * 256 + threadIdx.x;
    if (n >= N) return;
    int deg = offs[n + 1] - offs[n];
    int b = ((deg < 63 ? deg : 63) << 3) | ((n >> 4) & 7);
    int pos = atomicAdd(&dbkt[b], 1);
    perm[pos] = n;
}

// ---------------- fused GAT edge-softmax + aggregation -----------------------
// 16 lanes per dst node, 4 nodes per wave (degree-sorted via perm so the 4
// nodes share one degree -> wave-max == mean, ~9% tail waste vs ~30%).
// 4 edges per group-iteration: 4 independent csr loads + 4 independent
// p-row gathers in flight (MLP=4), next-iteration csr prefetch. Score
// partial per edge = fma(d,0.6a)+fma(|d|,0.4a); 4 independent DPP
// row_ror reduce chains; inactive slots masked branchlessly.
// EPI 0 (D=128): m2 = gelu(h+bvec) -> hi/lo bf16.  EPI 1 (D=64): fp32 out.
template <int D, int EPI>
__global__ __launch_bounds__(256) void gat_agg(
    const float* __restrict__ q, const unsigned short* __restrict__ p,
    const float* __restrict__ a, const float* __restrict__ bvec,
    const int* __restrict__ offs, const int* __restrict__ csr_src,
    const int* __restrict__ perm,
    float* __restrict__ out, unsigned short* __restrict__ mhi,
    unsigned short* __restrict__ mlo, int N)
{
    constexpr int VPL = D / 16;   // dims per lane: 8 (D=128) or 4 (D=64)
    const int t = threadIdx.x;
    const int lane = t & 63;
    const int sl = lane & 15;
    const int base = sl * VPL;
    const int nidx = blockIdx.x * 16 + ((t >> 6) << 2) + (lane >> 4);
    const bool valid = nidx < N;
    const int node = valid ? perm[nidx] : 0;

    float qv[VPL], a6[VPL], a4[VPL], acc[VPL];
#pragma unroll
    for (int v = 0; v < VPL; v++) { qv[v] = 0.f; acc[v] = 0.f; }
    if (valid) {
        const float* qp = q + (size_t)node * D + base;
        float4 q0 = *reinterpret_cast<const float4*>(qp);
        qv[0] = q0.x; qv[1] = q0.y; qv[2] = q0.z; qv[3] = q0.w;
        if constexpr (VPL == 8) {
            float4 q1 = *reinterpret_cast<const float4*>(qp + 4);
            qv[4] = q1.x; qv[5] = q1.y; qv[6] = q1.z; qv[7] = q1.w;
        }
    }
#pragma unroll
    for (int v = 0; v < VPL; v++) {
        float av = a[base + v];
        a6[v] = 0.6f * av;
        a4[v] = 0.4f * av;
    }

    float denom = 0.f;
    int e  = valid ? offs[node] : 0;
    int e1 = valid ? offs[node + 1] : 0;

    // prologue: csr indices for the first 4-edge batch (clamped to a valid slot)
    int s0 = csr_src[(e + 0 < e1) ? e + 0 : 0];
    int s1 = csr_src[(e + 1 < e1) ? e + 1 : 0];
    int s2 = csr_src[(e + 2 < e1) ? e + 2 : 0];
    int s3 = csr_src[(e + 3 < e1) ? e + 3 : 0];

    float pv[4][VPL];

    while (__any(e < e1)) {
        const bool a0 = (e + 0) < e1, a1b = (e + 1) < e1,
                   a2 = (e + 2) < e1, a3 = (e + 3) < e1;

        // issue the 4 p-row gathers (independent; 16 lanes x 16B = one row)
        if constexpr (D == 128) {
            uint4 u0 = *reinterpret_cast<const uint4*>(p + (size_t)s0 * 128 + base);
            uint4 u1 = *reinterpret_cast<const uint4*>(p + (size_t)s1 * 128 + base);
            uint4 u2 = *reinterpret_cast<const uint4*>(p + (size_t)s2 * 128 + base);
            uint4 u3 = *reinterpret_cast<const uint4*>(p + (size_t)s3 * 128 + base);
            pv[0][0] = __uint_as_float(u0.x << 16); pv[0][1] = __uint_as_float(u0.x & 0xffff0000u);
            pv[0][2] = __uint_as_float(u0.y << 16); pv[0][3] = __uint_as_float(u0.y & 0xffff0000u);
            pv[0][4] = __uint_as_float(u0.z << 16); pv[0][5] = __uint_as_float(u0.z & 0xffff0000u);
            pv[0][6] = __uint_as_float(u0.w << 16); pv[0][7] = __uint_as_float(u0.w & 0xffff0000u);
            pv[1][0] = __uint_as_float(u1.x << 16); pv[1][1] = __uint_as_float(u1.x & 0xffff0000u);
            pv[1][2] = __uint_as_float(u1.y << 16); pv[1][3] = __uint_as_float(u1.y & 0xffff0000u);
            pv[1][4] = __uint_as_float(u1.z << 16); pv[1][5] = __uint_as_float(u1.z & 0xffff0000u);
            pv[1][6] = __uint_as_float(u1.w << 16); pv[1][7] = __uint_as_float(u1.w & 0xffff0000u);
            pv[2][0] = __uint_as_float(u2.x << 16); pv[2][1] = __uint_as_float(u2.x & 0xffff0000u);
            pv[2][2] = __uint_as_float(u2.y << 16); pv[2][3] = __uint_as_float(u2.y & 0xffff0000u);
            pv[2][4] = __uint_as_float(u2.z << 16); pv[2][5] = __uint_as_float(u2.z & 0xffff0000u);
            pv[2][6] = __uint_as_float(u2.w << 16); pv[2][7] = __uint_as_float(u2.w & 0xffff0000u);
            pv[3][0] = __uint_as_float(u3.x << 16); pv[3][1] = __uint_as_float(u3.x & 0xffff0000u);
            pv[3][2] = __uint_as_float(u3.y << 16); pv[3][3] = __uint_as_float(u3.y & 0xffff0000u);
            pv[3][4] = __uint_as_float(u3.z << 16); pv[3][5] = __uint_as_float(u3.z & 0xffff0000u);
            pv[3][6] = __uint_as_float(u3.w << 16); pv[3][7] = __uint_as_float(u3.w & 0xffff0000u);
        } else {
            uint2 u0 = *reinterpret_cast<const uint2*>(p + (size_t)s0 * 64 + base);
            uint2 u1 = *reinterpret_cast<const uint2*>(p + (size_t)s1 * 64 + base);
            uint2 u2 = *reinterpret_cast<const uint2*>(p + (size_t)s2 * 64 + base);
            uint2 u3 = *reinterpret_cast<const uint2*>(p + (size_t)s3 * 64 + base);
            pv[0][0] = __uint_as_float(u0.x << 16); pv[0][1] = __uint_as_float(u0.x & 0xffff0000u);
            pv[0][2] = __uint_as_float(u0.y << 16); pv[0][3] = __uint_as_float(u0.y & 0xffff0000u);
            pv[1][0] = __uint_as_float(u1.x << 16); pv[1][1] = __uint_as_float(u1.x & 0xffff0000u);
            pv[1][2] = __uint_as_float(u1.y << 16); pv[1][3] = __uint_as_float(u1.y & 0xffff0000u);
            pv[2][0] = __uint_as_float(u2.x << 16); pv[2][1] = __uint_as_float(u2.x & 0xffff0000u);
            pv[2][2] = __uint_as_float(u2.y << 16); pv[2][3] = __uint_as_float(u2.y & 0xffff0000u);
            pv[3][0] = __uint_as_float(u3.x << 16); pv[3][1] = __uint_as_float(u3.x & 0xffff0000u);
            pv[3][2] = __uint_as_float(u3.y << 16); pv[3][3] = __uint_as_float(u3.y & 0xffff0000u);
        }

        // prefetch next batch's csr indices (hides index->gather latency)
        const int en = e + 4;
        const int n0 = csr_src[(en + 0 < e1) ? en + 0 : 0];
        const int n1 = csr_src[(en + 1 < e1) ? en + 1 : 0];
        const int n2 = csr_src[(en + 2 < e1) ? en + 2 : 0];
        const int n3 = csr_src[(en + 3 < e1) ? en + 3 : 0];

        // score partials (4 independent fma chains)
        float pa0 = 0.f, pa1 = 0.f, pa2 = 0.f, pa3 = 0.f;
#pragma unroll
        for (int v = 0; v < VPL; v++) {
            float d0 = qv[v] + pv[0][v];
            float d1 = qv[v] + pv[1][v];
            float d2 = qv[v] + pv[2][v];
            float d3 = qv[v] + pv[3][v];
            pa0 = fmaf(d0, a6[v], pa0); pa0 = fmaf(fabsf(d0), a4[v], pa0);
            pa1 = fmaf(d1, a6[v], pa1); pa1 = fmaf(fabsf(d1), a4[v], pa1);
            pa2 = fmaf(d2, a6[v], pa2); pa2 = fmaf(fabsf(d2), a4[v], pa2);
            pa3 = fmaf(d3, a6[v], pa3); pa3 = fmaf(fabsf(d3), a4[v], pa3);
        }

        // 4 independent 16-lane reduce chains (pipeline through DPP)
        float r0 = row16_sum(pa0);
        float r1 = row16_sum(pa1);
        float r2 = row16_sum(pa2);
        float r3 = row16_sum(pa3);

        float esm0 = a0  ? __expf(r0) : 0.f;
        float esm1 = a1b ? __expf(r1) : 0.f;
        float esm2 = a2  ? __expf(r2) : 0.f;
        float esm3 = a3  ? __expf(r3) : 0.f;
        denom += (esm0 + esm1) + (esm2 + esm3);
#pragma unroll
        for (int v = 0; v < VPL; v++) {
            acc[v] = fmaf(esm0, pv[0][v], acc[v]);
            acc[v] = fmaf(esm1, pv[1][v], acc[v]);
            acc[v] = fmaf(esm2, pv[2][v], acc[v]);
            acc[v] = fmaf(esm3, pv[3][v], acc[v]);
        }

        e = en;
        s0 = n0; s1 = n1; s2 = n2; s3 = n3;
    }

    if (!valid) return;
    float inv = (denom != 0.f) ? 1.f / denom : 0.f;  // zero-degree -> agg = 0
    if constexpr (EPI == 0) {
        union { unsigned short us[8]; uint4 v; } H, L;
#pragma unroll
        for (int v = 0; v < VPL; v++) {
            float g = gelu_erf(acc[v] * inv + bvec[base + v]);
            H.us[v] = f2bf(g);
            L.us[v] = f2bf(g - bf2f(H.us[v]));
        }
        *reinterpret_cast<uint4*>(mhi + (size_t)node * 128 + base) = H.v;
        *reinterpret_cast<uint4*>(mlo + (size_t)node * 128 + base) = L.v;
    } else {
        union { float f[4]; float4 v; } O;
#pragma unroll
        for (int v = 0; v < VPL; v++) O.f[v] = acc[v] * inv + bvec[base + v];
        *reinterpret_cast<float4*>(out + (size_t)node * D + base) = O.v;
    }
}

// ---------------- launch ------------------------------------------------------
extern "C" void kernel_launch(void* const* d_in, const int* in_sizes, int n_in,
                              void* d_out, int out_size, void* d_ws, size_t ws_size,
                              hipStream_t stream)
{
    const float* x     = (const float*)d_in[0];
    const float* W0    = (const float*)d_in[1];
    const float* b0    = (const float*)d_in[2];
    const float* Wq1   = (const float*)d_in[3];
    const float* bq1   = (const float*)d_in[4];
    const float* Wp1   = (const float*)d_in[5];
    const float* bp1   = (const float*)d_in[6];
    const float* a1    = (const float*)d_in[7];
    const float* bg2   = (const float*)d_in[8];
    const float* Wq2   = (const float*)d_in[9];
    const float* bq2   = (const float*)d_in[10];
    const float* Wp2   = (const float*)d_in[11];
    const float* bp2   = (const float*)d_in[12];
    const float* a2    = (const float*)d_in[13];
    const float* b_out = (const float*)d_in[14];
    const int*   src   = (const int*)d_in[15];
    const int*   dst   = (const int*)d_in[16];

    const int N = in_sizes[0] / 128;
    const int E = in_sizes[15];
    float* out = (float*)d_out;

    // workspace carve
    float* q_buf        = (float*)d_ws;                      // N*128 f32
    unsigned short* pb  = (unsigned short*)(q_buf + (size_t)N * 128);  // N*128 bf16
    unsigned short* Mhi = pb + (size_t)N * 128;
    unsigned short* Mlo = Mhi + (size_t)N * 128;
    unsigned short* P0  = Mlo + (size_t)N * 128;
    unsigned short* Pq1 = P0  + 128 * 128 * 2;
    unsigned short* Pp1 = Pq1 + 128 * 128 * 2;
    unsigned short* Pq2 = Pp1 + 128 * 128 * 2;
    unsigned short* Pp2 = Pq2 + 128 * 64 * 2;
    int* offs    = (int*)(Pp2 + 128 * 64 * 2);
    int* csr_src = offs + (N + 2);
    const int CB = (N + 15) / 16;          // coarse bins (<= 4096 for N<=65536)
    const int M  = CB * 64;
    int* gh    = csr_src + E;
    int* gscan = gh + M;
    int* bsum  = gscan + M;                // 1024 ints
    int* dbkt  = bsum + 1024;              // 512 degree-bucket counters
    int* perm  = dbkt + 512;               // N ints, degree-sorted node order
    // pairs aliases q_buf (dead until gemm layer-1); int2-aligned (base of ws)
    int2* pairs = (int2*)q_buf;

    const int NB1 = (M + 255) / 256;       // <= 1024

    // 1) weight prepack
    pack_w<<<dim3(64, 5), 256, 0, stream>>>(W0, Wq1, Wp1, Wq2, Wp2,
                                            P0, Pq1, Pp1, Pq2, Pp2);
    // 2-7) CSR build (atomic-free two-level counting sort)
    hist_coarse<<<64, 256, 0, stream>>>(dst, gh, dbkt, E, CB);
    scan1_kernel<<<NB1, 256, 0, stream>>>(gh, gscan, bsum, M);
    scan2_kernel<<<1, 1024, 0, stream>>>(bsum, NB1);
    scan3_kernel<<<NB1, 256, 0, stream>>>(gscan, bsum, M);
    scatter_coarse<<<64, 256, 0, stream>>>(src, dst, gscan, pairs, E, CB);
    finalize_kernel<<<CB, 256, 0, stream>>>(pairs, gscan, offs, csr_src, dbkt, N, E, CB);
    // 8-9) degree-sorted node permutation (load balance for gat_agg)
    scan_dbkt<<<1, 512, 0, stream>>>(dbkt);
    scatter_perm<<<(N + 255) / 256, 256, 0, stream>>>(offs, dbkt, perm, N);

    const int GB64 = (N + 63) / 64;
    const int GGAT = (N + 15) / 16;

    // 10) layer 0: m1 = gelu(x@W0 + b0) -> Mhi/Mlo
    mfma_gemm<128, false, 0><<<GB64, 256, 0, stream>>>(
        x, nullptr, nullptr, P0, b0, nullptr, nullptr,
        nullptr, nullptr, Mhi, Mlo, N);
    // 11) layer 1 projections: q1 fp32 + p1 bf16 in ONE pass over A
    mfma_gemm<128, true, 1><<<GB64, 256, 0, stream>>>(
        nullptr, Mhi, Mlo, Pq1, bq1, Pp1, bp1,
        q_buf, pb, nullptr, nullptr, N);
    // 12) layer 1 GAT -> m2 = gelu(h1 + bg2) -> Mhi/Mlo
    gat_agg<128, 0><<<GGAT, 256, 0, stream>>>(
        q_buf, pb, a1, bg2, offs, csr_src, perm,
        nullptr, Mhi, Mlo, N);
    // 13) layer 2 projections: q2 fp32 + p2 bf16 in ONE pass over A
    mfma_gemm<64, true, 1><<<GB64, 256, 0, stream>>>(
        nullptr, Mhi, Mlo, Pq2, bq2, Pp2, bp2,
        q_buf, pb, nullptr, nullptr, N);
    // 14) layer 2 GAT + b_out -> d_out
    gat_agg<64, 1><<<GGAT, 256, 0, stream>>>(
        q_buf, pb, a2, b_out, offs, csr_src, perm,
        out, nullptr, nullptr, N);
}

// Round 5
// 290.571 us; speedup vs baseline: 1.6056x; 1.6056x over previous
//
#include <hip/hip_runtime.h>
#include <hip/hip_bf16.h>
#include <math.h>

// GAT 2-layer fused pipeline for MI355X (gfx950).
// Round-14: revert r13's degree-perm (cross-XCD atomic contention on 512
// hot counters made finalize 121 us, VALUBusy 0.7%). gat_agg back to r12
// natural-order form (48 us, best measured). finalize_kernel rewritten as
// wave-per-bin ballot ranking: zero LDS, zero atomics (r12 finalize had
// 300k LDS bank conflicts from 16-bit packed LDS-atomic hist/rank on 8
// words). Counts via __ballot histograms, stable rank via mbcnt-style
// popcount + one ds_bpermute cursor lookup per chunk.
// GEMM (64-row single-pass-A) and rest of CSR build unchanged from r12.

#define SLOPE 0.2f

typedef __attribute__((ext_vector_type(8))) __bf16 bf16x8;
typedef __attribute__((ext_vector_type(4))) float f32x4;

__device__ __forceinline__ float gelu_erf(float x) {
    return 0.5f * x * (1.0f + erff(x * 0.70710678118654752f));
}

__device__ __forceinline__ unsigned short f2bf(float f) {  // RNE
    unsigned int u = __float_as_uint(f);
    return (unsigned short)((u + 0x7fffu + ((u >> 16) & 1u)) >> 16);
}
__device__ __forceinline__ float bf2f(unsigned short h) {
    return __uint_as_float((unsigned int)h << 16);
}

// 16-lane (row) all-reduce sum via DPP row_ror 1,2,4,8; every lane of the
// row ends with the row's sum. Chains over different inputs are independent.
__device__ __forceinline__ float row16_sum(float x) {
    x += __int_as_float(__builtin_amdgcn_update_dpp(0, __float_as_int(x), 0x121, 0xF, 0xF, true));
    x += __int_as_float(__builtin_amdgcn_update_dpp(0, __float_as_int(x), 0x122, 0xF, 0xF, true));
    x += __int_as_float(__builtin_amdgcn_update_dpp(0, __float_as_int(x), 0x124, 0xF, 0xF, true));
    x += __int_as_float(__builtin_amdgcn_update_dpp(0, __float_as_int(x), 0x128, 0xF, 0xF, true));
    return x;
}

// XOR swizzle for LDS planes with 256B row stride: spreads the 16-row
// column slice of a ds_read_b128 across 8 distinct 16B slots.
__device__ __forceinline__ int swz(int off) { return off ^ ((off >> 4) & 0x70); }

// ---------------- weight prepack ---------------------------------------------
// Pack index i = ((ct*4+ks)*64 + lane)*8 + j  ->  W[k][n],
// k = ks*32 + (lane>>4)*8 + j,  n = ct*16 + (lane&15).  hi at [i], lo at [CE+i].
__global__ __launch_bounds__(256) void pack_w(
    const float* __restrict__ W0,  const float* __restrict__ Wq1,
    const float* __restrict__ Wp1, const float* __restrict__ Wq2,
    const float* __restrict__ Wp2,
    unsigned short* __restrict__ P0,  unsigned short* __restrict__ Pq1,
    unsigned short* __restrict__ Pp1, unsigned short* __restrict__ Pq2,
    unsigned short* __restrict__ Pp2)
{
    const float* W; unsigned short* P; int C;
    switch (blockIdx.y) {
        case 0:  W = W0;  P = P0;  C = 128; break;
        case 1:  W = Wq1; P = Pq1; C = 128; break;
        case 2:  W = Wp1; P = Pp1; C = 128; break;
        case 3:  W = Wq2; P = Pq2; C = 64;  break;
        default: W = Wp2; P = Pp2; C = 64;  break;
    }
    int i = blockIdx.x * 256 + threadIdx.x;
    int CE = C * 128;
    if (i >= CE) return;
    int j = i & 7, l = (i >> 3) & 63, ks = (i >> 9) & 3, ct = i >> 11;
    int k = ks * 32 + ((l >> 4) << 3) + j;
    int n = ct * 16 + (l & 15);
    float v = W[k * C + n];
    unsigned short hb = f2bf(v);
    P[i] = hb;
    P[CE + i] = f2bf(v - bf2f(hb));
}

// ---------------- MFMA GEMM -------------------------------------------------
// Block = 64 rows x ALL output cols; 4 waves split the col-tiles.
// A panel (64x128, hi+lo bf16 = 32 KB) staged in LDS once (swizzled);
// W fragments streamed from packed global (L2-resident).
// EPI 0: single matrix, out = gelu -> o1hi/o1lo (layer 0, A = fp32).
// EPI 1: TWO matrices: waves 0-1 -> q fp32 (direct), waves 2-3 -> p bf16
//        (LDS-bounced for coalesced 16B stores).
template <int C, bool TWO, int EPI>
__global__ __launch_bounds__(256) void mfma_gemm(
    const float* __restrict__ Af,
    const unsigned short* __restrict__ AHg, const unsigned short* __restrict__ ALg,
    const unsigned short* __restrict__ P1, const float* __restrict__ b1,
    const unsigned short* __restrict__ P2, const float* __restrict__ b2,
    float* __restrict__ outq, unsigned short* __restrict__ outp,
    unsigned short* __restrict__ o1hi, unsigned short* __restrict__ o1lo,
    int N)
{
    constexpr int CE  = C * 128;
    constexpr int CTT = (TWO ? 2 : 1) * (C / 16);   // total col-tiles
    constexpr int CTW = CTT / 4;                    // tiles per wave
    constexpr int QCT = C / 16;                     // tiles in first matrix

    __shared__ __align__(16) unsigned char lds[32768]; // hi plane [0,16K), lo [16K,32K)

    const int t = threadIdx.x;
    const int lane = t & 63;
    const int w = t >> 6;
    const int row0 = blockIdx.x * 64;
    const int mcol = lane & 15;
    const int hk = lane >> 4;

    // ---- stage A (64 rows x 128 dims) as hi/lo bf16 into LDS ----
    if constexpr (EPI == 0) {
#pragma unroll
        for (int i = 0; i < 8; i++) {
            int idx = t + i * 256;            // float4 index, 2048 total
            int row = idx >> 5;               // 32 float4 per row
            int gr = row0 + row;
            float4 v = make_float4(0.f, 0.f, 0.f, 0.f);
            if (gr < N) v = *reinterpret_cast<const float4*>(Af + (size_t)gr * 128 + (idx & 31) * 4);
            const float* f = reinterpret_cast<const float*>(&v);
            unsigned int h[4], l[4];
#pragma unroll
            for (int j = 0; j < 4; j++) {
                unsigned short hb = f2bf(f[j]);
                h[j] = hb;
                l[j] = f2bf(f[j] - bf2f(hb));
            }
            int so = swz(row * 256 + (idx & 31) * 8);
            *reinterpret_cast<uint2*>(&lds[so])         = make_uint2(h[0] | (h[1] << 16), h[2] | (h[3] << 16));
            *reinterpret_cast<uint2*>(&lds[16384 + so]) = make_uint2(l[0] | (l[1] << 16), l[2] | (l[3] << 16));
        }
    } else {
#pragma unroll
        for (int i = 0; i < 4; i++) {
            int idx = t + i * 256;            // uint4 index, 1024 per plane
            int row = idx >> 4;               // 16 uint4 per row
            int gr = row0 + row;
            uint4 vh = make_uint4(0, 0, 0, 0), vl = make_uint4(0, 0, 0, 0);
            if (gr < N) {
                vh = *reinterpret_cast<const uint4*>(AHg + (size_t)gr * 128 + (idx & 15) * 8);
                vl = *reinterpret_cast<const uint4*>(ALg + (size_t)gr * 128 + (idx & 15) * 8);
            }
            int so = swz(row * 256 + (idx & 15) * 16);
            *reinterpret_cast<uint4*>(&lds[so])         = vh;
            *reinterpret_cast<uint4*>(&lds[16384 + so]) = vl;
        }
    }
    __syncthreads();

    f32x4 acc[CTW][4];
#pragma unroll
    for (int c = 0; c < CTW; c++)
#pragma unroll
        for (int rf = 0; rf < 4; rf++) acc[c][rf] = (f32x4){0.f, 0.f, 0.f, 0.f};

#pragma unroll
    for (int ks = 0; ks < 4; ks++) {
        bf16x8 ah[4], al[4];
#pragma unroll
        for (int rf = 0; rf < 4; rf++) {
            int so = swz((rf * 16 + mcol) * 256 + ks * 64 + hk * 16);
            ah[rf] = *reinterpret_cast<const bf16x8*>(&lds[so]);
            al[rf] = *reinterpret_cast<const bf16x8*>(&lds[16384 + so]);
        }
#pragma unroll
        for (int c = 0; c < CTW; c++) {
            int ctg = w * CTW + c;
            bool isq = (!TWO) || (ctg < QCT);
            int ct = isq ? ctg : ctg - QCT;
            const unsigned short* P = isq ? P1 : P2;
            const unsigned short* Wp = P + ((ct * 4 + ks) * 64 + lane) * 8;
            bf16x8 bh = *reinterpret_cast<const bf16x8*>(Wp);
            bf16x8 bl = *reinterpret_cast<const bf16x8*>(Wp + CE);
#pragma unroll
            for (int rf = 0; rf < 4; rf++) {
                acc[c][rf] = __builtin_amdgcn_mfma_f32_16x16x32_bf16(ah[rf], bh, acc[c][rf], 0, 0, 0);
                acc[c][rf] = __builtin_amdgcn_mfma_f32_16x16x32_bf16(al[rf], bh, acc[c][rf], 0, 0, 0);
                acc[c][rf] = __builtin_amdgcn_mfma_f32_16x16x32_bf16(ah[rf], bl, acc[c][rf], 0, 0, 0);
            }
        }
    }

    __syncthreads();   // all A ds_reads done; LDS reused for epilogue staging

    // epilogue: C/D layout col=lane&15, row=(lane>>4)*4+reg
    if constexpr (EPI == 0) {
#pragma unroll
        for (int c = 0; c < CTW; c++) {
            int col = (w * CTW + c) * 16 + mcol;
            float bv = b1[col];
#pragma unroll
            for (int rf = 0; rf < 4; rf++) {
#pragma unroll
                for (int r = 0; r < 4; r++) {
                    int row = rf * 16 + hk * 4 + r;
                    float v = gelu_erf(acc[c][rf][r] + bv);
                    unsigned short hb = f2bf(v);
                    int bo = row * 256 + col * 2;
                    *reinterpret_cast<unsigned short*>(&lds[swz(bo)])         = hb;
                    *reinterpret_cast<unsigned short*>(&lds[16384 + swz(bo)]) = f2bf(v - bf2f(hb));
                }
            }
        }
        __syncthreads();
#pragma unroll
        for (int i = 0; i < 8; i++) {
            int idx = t + i * 256;          // 2048 uint4: hi 0..1023, lo 1024..2047
            int pl = idx >> 10;
            int j = idx & 1023;
            int row = j >> 4;
            int gr = row0 + row;
            if (gr < N) {
                uint4 v = *reinterpret_cast<const uint4*>(&lds[pl * 16384 + swz(row * 256 + (j & 15) * 16)]);
                unsigned short* dp = pl ? o1lo : o1hi;
                *reinterpret_cast<uint4*>(dp + (size_t)gr * 128 + (j & 15) * 8) = v;
            }
        }
    } else {
#pragma unroll
        for (int c = 0; c < CTW; c++) {
            int ctg = w * CTW + c;
            bool isq = ctg < QCT;
            int ct = isq ? ctg : ctg - QCT;
            int col = ct * 16 + mcol;
            float bv = (isq ? b1 : b2)[col];
#pragma unroll
            for (int rf = 0; rf < 4; rf++) {
#pragma unroll
                for (int r = 0; r < 4; r++) {
                    int row = rf * 16 + hk * 4 + r;
                    int gr = row0 + row;
                    float v = acc[c][rf][r] + bv;
                    if (isq) {
                        if (gr < N) outq[(size_t)gr * C + col] = v;   // 4B x 16 lanes = full line
                    } else {
                        *reinterpret_cast<unsigned short*>(&lds[swz(row * 256 + col * 2)]) = f2bf(v);
                    }
                }
            }
        }
        __syncthreads();
        constexpr int SLOTS = C / 8;        // uint4 slots per row (16 or 8)
#pragma unroll
        for (int i = 0; i < (64 * SLOTS) / 256; i++) {
            int idx = t + i * 256;
            int row = idx / SLOTS;
            int sl = idx % SLOTS;
            int gr = row0 + row;
            if (gr < N)
                *reinterpret_cast<uint4*>(outp + (size_t)gr * C + sl * 8) =
                    *reinterpret_cast<const uint4*>(&lds[swz(row * 256 + sl * 16)]);
        }
    }
}

// ---------------- CSR build: atomic-free two-level counting sort -------------
// Coarse bin = dst >> 4 (16 nodes per bin), CB = ceil(N/16) <= 4096.
// 64 edge-blocks; gh[bin*64 + blk] = count (bin-major for linear scan).

__global__ __launch_bounds__(256) void hist_coarse(
    const int* __restrict__ dst, int* __restrict__ gh, int E, int CB)
{
    __shared__ int cnt[4096];
    const int blk = blockIdx.x;     // 0..63
    const int t = threadIdx.x;
    for (int b = t; b < CB; b += 256) cnt[b] = 0;
    __syncthreads();
    const int epb = (E + 63) / 64;
    const int s = blk * epb;
    const int e_ = (s + epb < E) ? s + epb : E;
    for (int i = s + t; i < e_; i += 256)
        atomicAdd(&cnt[dst[i] >> 4], 1);
    __syncthreads();
    for (int b = t; b < CB; b += 256)
        gh[b * 64 + blk] = cnt[b];
}

// hierarchical exclusive scan over M = CB*64 values: gh -> gscan
__global__ __launch_bounds__(256) void scan1_kernel(const int* __restrict__ gh,
                                                    int* __restrict__ gscan,
                                                    int* __restrict__ bsum, int M)
{
    __shared__ int lds[256];
    int t = threadIdx.x;
    int i = blockIdx.x * 256 + t;
    int v = (i < M) ? gh[i] : 0;
    lds[t] = v;
    __syncthreads();
    int x = v;
    for (int off = 1; off < 256; off <<= 1) {
        int y = (t >= off) ? lds[t - off] : 0;
        __syncthreads();
        x += y;
        lds[t] = x;
        __syncthreads();
    }
    if (i < M) gscan[i] = x - v;
    if (t == 255) bsum[blockIdx.x] = x;
}

__global__ __launch_bounds__(1024) void scan2_kernel(int* __restrict__ bsum, int NB)
{
    __shared__ int lds[1024];
    int t = threadIdx.x;
    int v = (t < NB) ? bsum[t] : 0;
    lds[t] = v;
    __syncthreads();
    int x = v;
    for (int off = 1; off < 1024; off <<= 1) {
        int y = (t >= off) ? lds[t - off] : 0;
        __syncthreads();
        x += y;
        lds[t] = x;
        __syncthreads();
    }
    if (t < NB) bsum[t] = x - v;
}

__global__ __launch_bounds__(256) void scan3_kernel(int* __restrict__ gscan,
                                                    const int* __restrict__ bsum, int M)
{
    int i = blockIdx.x * 256 + threadIdx.x;
    if (i < M) gscan[i] += bsum[blockIdx.x];
}

// scatter edges into coarse-bin-grouped (dst,src) pairs; LDS cursors only.
__global__ __launch_bounds__(256) void scatter_coarse(
    const int* __restrict__ src, const int* __restrict__ dst,
    const int* __restrict__ gscan, int2* __restrict__ pairs, int E, int CB)
{
    __shared__ int cur[4096];
    const int blk = blockIdx.x;     // 0..63
    const int t = threadIdx.x;
    for (int b = t; b < CB; b += 256)
        cur[b] = gscan[b * 64 + blk];
    __syncthreads();
    const int epb = (E + 63) / 64;
    const int s = blk * epb;
    const int e_ = (s + epb < E) ? s + epb : E;
    for (int i = s + t; i < e_; i += 256) {
        int d = dst[i];
        int sv = src[i];
        int pos = atomicAdd(&cur[d >> 4], 1);   // LDS atomic
        pairs[pos] = make_int2(d, sv);
    }
}

// one WAVE per coarse bin: ballot-histogram counts, exclusive scan, stable
// ranks via popcount(ballot & lanemask_lt) + per-chunk running cursor in
// lane j (fetched per-lane with one ds_bpermute). Zero LDS, zero atomics.
__global__ __launch_bounds__(256) void finalize_kernel(
    const int2* __restrict__ pairs, const int* __restrict__ gscan,
    int* __restrict__ offs, int* __restrict__ csr_src, int N, int E, int CB)
{
    const int wid = blockIdx.x * 4 + (threadIdx.x >> 6);   // bin index
    const int lane = threadIdx.x & 63;
    if (wid >= CB) return;                                 // wave-uniform exit

    const int s    = gscan[wid * 64];
    const int e_   = (wid + 1 < CB) ? gscan[(wid + 1) * 64] : E;
    const int base = wid * 16;
    const unsigned long long ltmask = (lane == 63) ? ~0ull >> 1
                                                   : (1ull << lane) - 1ull;

    // pass 1: per-node counts via ballot histogram (rc[j] wave-uniform)
    int rc[16];
#pragma unroll
    for (int j = 0; j < 16; j++) rc[j] = 0;
    for (int c0 = s; c0 < e_; c0 += 64) {
        int i = c0 + lane;
        int d = (i < e_) ? pairs[i].x - base : -1;
#pragma unroll
        for (int j = 0; j < 16; j++)
            rc[j] += (int)__popcll(__ballot(d == j));
    }

    // exclusive scan -> pref[]; vector copy in lane j for bpermute lookups
    int pref[16];
    int run = s;
#pragma unroll
    for (int j = 0; j < 16; j++) { pref[j] = run; run += rc[j]; }
    int pref_v = 0;
#pragma unroll
    for (int j = 0; j < 16; j++) pref_v = (lane == j) ? pref[j] : pref_v;

    if (lane < 16 && base + lane < N) offs[base + lane] = pref_v;
    if (wid == CB - 1 && lane == 16) offs[N] = E;

    // pass 2: stable rank + contiguous scatter
    int rcv = 0;                       // lane j holds running count of node j
    for (int c0 = s; c0 < e_; c0 += 64) {
        int i = c0 + lane;
        const bool act = i < e_;
        int2 pr = act ? pairs[i] : make_int2(base - 1, 0);
        int d = pr.x - base;           // -1 for inactive lanes
        unsigned long long msel = 0;
        int addcnt = 0;
#pragma unroll
        for (int j = 0; j < 16; j++) {
            unsigned long long m = __ballot(d == j);
            if (d == j) msel = m;
            if (lane == j) addcnt = (int)__popcll(m);
        }
        int subrank = (int)__popcll(msel & ltmask);
        int posbase = __builtin_amdgcn_ds_bpermute(d * 4, pref_v + rcv);
        if (act) csr_src[posbase + subrank] = pr.y;
        rcv += addcnt;
    }
}

// ---------------- fused GAT edge-softmax + aggregation -----------------------
// 16 lanes per dst node, 4 nodes per wave, 4 edges per group-iteration:
// 4 independent csr loads + 4 independent p-row gathers in flight (MLP=4),
// next-iteration csr indices prefetched. Score partial per edge =
// fma(d,0.6a)+fma(|d|,0.4a) (leaky(x)=0.6x+0.4|x|); 4 independent 4-stage
// DPP row_ror reduce chains. Inactive slots masked branchlessly via
// esm = act ? es : 0 (garbage reduces stay inside their own 16-lane group).
// EPI 0 (D=128): m2 = gelu(h+bvec) packed hi/lo bf16.  EPI 1 (D=64): fp32 out.
template <int D, int EPI>
__global__ __launch_bounds__(256) void gat_agg(
    const float* __restrict__ q, const unsigned short* __restrict__ p,
    const float* __restrict__ a, const float* __restrict__ bvec,
    const int* __restrict__ offs, const int* __restrict__ csr_src,
    float* __restrict__ out, unsigned short* __restrict__ mhi,
    unsigned short* __restrict__ mlo, int N)
{
    constexpr int VPL = D / 16;   // dims per lane: 8 (D=128) or 4 (D=64)
    const int t = threadIdx.x;
    const int lane = t & 63;
    const int sl = lane & 15;
    const int base = sl * VPL;
    const int node = blockIdx.x * 16 + ((t >> 6) << 2) + (lane >> 4);
    const bool valid = node < N;

    float qv[VPL], a6[VPL], a4[VPL], acc[VPL];
#pragma unroll
    for (int v = 0; v < VPL; v++) { qv[v] = 0.f; acc[v] = 0.f; }
    if (valid) {
        const float* qp = q + (size_t)node * D + base;
        float4 q0 = *reinterpret_cast<const float4*>(qp);
        qv[0] = q0.x; qv[1] = q0.y; qv[2] = q0.z; qv[3] = q0.w;
        if constexpr (VPL == 8) {
            float4 q1 = *reinterpret_cast<const float4*>(qp + 4);
            qv[4] = q1.x; qv[5] = q1.y; qv[6] = q1.z; qv[7] = q1.w;
        }
    }
#pragma unroll
    for (int v = 0; v < VPL; v++) {
        float av = a[base + v];
        a6[v] = 0.6f * av;
        a4[v] = 0.4f * av;
    }

    float denom = 0.f;
    int e  = valid ? offs[node] : 0;
    int e1 = valid ? offs[node + 1] : 0;

    // prologue: csr indices for the first 4-edge batch (clamped to a valid slot)
    int s0 = csr_src[(e + 0 < e1) ? e + 0 : 0];
    int s1 = csr_src[(e + 1 < e1) ? e + 1 : 0];
    int s2 = csr_src[(e + 2 < e1) ? e + 2 : 0];
    int s3 = csr_src[(e + 3 < e1) ? e + 3 : 0];

    float pv[4][VPL];

    while (__any(e < e1)) {
        const bool a0 = (e + 0) < e1, a1b = (e + 1) < e1,
                   a2 = (e + 2) < e1, a3 = (e + 3) < e1;

        // issue the 4 p-row gathers (independent; 16 lanes x 16B = one row)
        if constexpr (D == 128) {
            uint4 u0 = *reinterpret_cast<const uint4*>(p + (size_t)s0 * 128 + base);
            uint4 u1 = *reinterpret_cast<const uint4*>(p + (size_t)s1 * 128 + base);
            uint4 u2 = *reinterpret_cast<const uint4*>(p + (size_t)s2 * 128 + base);
            uint4 u3 = *reinterpret_cast<const uint4*>(p + (size_t)s3 * 128 + base);
            pv[0][0] = __uint_as_float(u0.x << 16); pv[0][1] = __uint_as_float(u0.x & 0xffff0000u);
            pv[0][2] = __uint_as_float(u0.y << 16); pv[0][3] = __uint_as_float(u0.y & 0xffff0000u);
            pv[0][4] = __uint_as_float(u0.z << 16); pv[0][5] = __uint_as_float(u0.z & 0xffff0000u);
            pv[0][6] = __uint_as_float(u0.w << 16); pv[0][7] = __uint_as_float(u0.w & 0xffff0000u);
            pv[1][0] = __uint_as_float(u1.x << 16); pv[1][1] = __uint_as_float(u1.x & 0xffff0000u);
            pv[1][2] = __uint_as_float(u1.y << 16); pv[1][3] = __uint_as_float(u1.y & 0xffff0000u);
            pv[1][4] = __uint_as_float(u1.z << 16); pv[1][5] = __uint_as_float(u1.z & 0xffff0000u);
            pv[1][6] = __uint_as_float(u1.w << 16); pv[1][7] = __uint_as_float(u1.w & 0xffff0000u);
            pv[2][0] = __uint_as_float(u2.x << 16); pv[2][1] = __uint_as_float(u2.x & 0xffff0000u);
            pv[2][2] = __uint_as_float(u2.y << 16); pv[2][3] = __uint_as_float(u2.y & 0xffff0000u);
            pv[2][4] = __uint_as_float(u2.z << 16); pv[2][5] = __uint_as_float(u2.z & 0xffff0000u);
            pv[2][6] = __uint_as_float(u2.w << 16); pv[2][7] = __uint_as_float(u2.w & 0xffff0000u);
            pv[3][0] = __uint_as_float(u3.x << 16); pv[3][1] = __uint_as_float(u3.x & 0xffff0000u);
            pv[3][2] = __uint_as_float(u3.y << 16); pv[3][3] = __uint_as_float(u3.y & 0xffff0000u);
            pv[3][4] = __uint_as_float(u3.z << 16); pv[3][5] = __uint_as_float(u3.z & 0xffff0000u);
            pv[3][6] = __uint_as_float(u3.w << 16); pv[3][7] = __uint_as_float(u3.w & 0xffff0000u);
        } else {
            uint2 u0 = *reinterpret_cast<const uint2*>(p + (size_t)s0 * 64 + base);
            uint2 u1 = *reinterpret_cast<const uint2*>(p + (size_t)s1 * 64 + base);
            uint2 u2 = *reinterpret_cast<const uint2*>(p + (size_t)s2 * 64 + base);
            uint2 u3 = *reinterpret_cast<const uint2*>(p + (size_t)s3 * 64 + base);
            pv[0][0] = __uint_as_float(u0.x << 16); pv[0][1] = __uint_as_float(u0.x & 0xffff0000u);
            pv[0][2] = __uint_as_float(u0.y << 16); pv[0][3] = __uint_as_float(u0.y & 0xffff0000u);
            pv[1][0] = __uint_as_float(u1.x << 16); pv[1][1] = __uint_as_float(u1.x & 0xffff0000u);
            pv[1][2] = __uint_as_float(u1.y << 16); pv[1][3] = __uint_as_float(u1.y & 0xffff0000u);
            pv[2][0] = __uint_as_float(u2.x << 16); pv[2][1] = __uint_as_float(u2.x & 0xffff0000u);
            pv[2][2] = __uint_as_float(u2.y << 16); pv[2][3] = __uint_as_float(u2.y & 0xffff0000u);
            pv[3][0] = __uint_as_float(u3.x << 16); pv[3][1] = __uint_as_float(u3.x & 0xffff0000u);
            pv[3][2] = __uint_as_float(u3.y << 16); pv[3][3] = __uint_as_float(u3.y & 0xffff0000u);
        }

        // prefetch next batch's csr indices (hides index->gather latency)
        const int en = e + 4;
        const int n0 = csr_src[(en + 0 < e1) ? en + 0 : 0];
        const int n1 = csr_src[(en + 1 < e1) ? en + 1 : 0];
        const int n2 = csr_src[(en + 2 < e1) ? en + 2 : 0];
        const int n3 = csr_src[(en + 3 < e1) ? en + 3 : 0];

        // score partials (4 independent fma chains)
        float pa0 = 0.f, pa1 = 0.f, pa2 = 0.f, pa3 = 0.f;
#pragma unroll
        for (int v = 0; v < VPL; v++) {
            float d0 = qv[v] + pv[0][v];
            float d1 = qv[v] + pv[1][v];
            float d2 = qv[v] + pv[2][v];
            float d3 = qv[v] + pv[3][v];
            pa0 = fmaf(d0, a6[v], pa0); pa0 = fmaf(fabsf(d0), a4[v], pa0);
            pa1 = fmaf(d1, a6[v], pa1); pa1 = fmaf(fabsf(d1), a4[v], pa1);
            pa2 = fmaf(d2, a6[v], pa2); pa2 = fmaf(fabsf(d2), a4[v], pa2);
            pa3 = fmaf(d3, a6[v], pa3); pa3 = fmaf(fabsf(d3), a4[v], pa3);
        }

        // 4 independent 16-lane reduce chains (pipeline through DPP)
        float r0 = row16_sum(pa0);
        float r1 = row16_sum(pa1);
        float r2 = row16_sum(pa2);
        float r3 = row16_sum(pa3);

        float esm0 = a0  ? __expf(r0) : 0.f;
        float esm1 = a1b ? __expf(r1) : 0.f;
        float esm2 = a2  ? __expf(r2) : 0.f;
        float esm3 = a3  ? __expf(r3) : 0.f;
        denom += (esm0 + esm1) + (esm2 + esm3);
#pragma unroll
        for (int v = 0; v < VPL; v++) {
            acc[v] = fmaf(esm0, pv[0][v], acc[v]);
            acc[v] = fmaf(esm1, pv[1][v], acc[v]);
            acc[v] = fmaf(esm2, pv[2][v], acc[v]);
            acc[v] = fmaf(esm3, pv[3][v], acc[v]);
        }

        e = en;
        s0 = n0; s1 = n1; s2 = n2; s3 = n3;
    }

    if (!valid) return;
    float inv = (denom != 0.f) ? 1.f / denom : 0.f;  // zero-degree -> agg = 0
    if constexpr (EPI == 0) {
        union { unsigned short us[8]; uint4 v; } H, L;
#pragma unroll
        for (int v = 0; v < VPL; v++) {
            float g = gelu_erf(acc[v] * inv + bvec[base + v]);
            H.us[v] = f2bf(g);
            L.us[v] = f2bf(g - bf2f(H.us[v]));
        }
        *reinterpret_cast<uint4*>(mhi + (size_t)node * 128 + base) = H.v;
        *reinterpret_cast<uint4*>(mlo + (size_t)node * 128 + base) = L.v;
    } else {
        union { float f[4]; float4 v; } O;
#pragma unroll
        for (int v = 0; v < VPL; v++) O.f[v] = acc[v] * inv + bvec[base + v];
        *reinterpret_cast<float4*>(out + (size_t)node * D + base) = O.v;
    }
}

// ---------------- launch ------------------------------------------------------
extern "C" void kernel_launch(void* const* d_in, const int* in_sizes, int n_in,
                              void* d_out, int out_size, void* d_ws, size_t ws_size,
                              hipStream_t stream)
{
    const float* x     = (const float*)d_in[0];
    const float* W0    = (const float*)d_in[1];
    const float* b0    = (const float*)d_in[2];
    const float* Wq1   = (const float*)d_in[3];
    const float* bq1   = (const float*)d_in[4];
    const float* Wp1   = (const float*)d_in[5];
    const float* bp1   = (const float*)d_in[6];
    const float* a1    = (const float*)d_in[7];
    const float* bg2   = (const float*)d_in[8];
    const float* Wq2   = (const float*)d_in[9];
    const float* bq2   = (const float*)d_in[10];
    const float* Wp2   = (const float*)d_in[11];
    const float* bp2   = (const float*)d_in[12];
    const float* a2    = (const float*)d_in[13];
    const float* b_out = (const float*)d_in[14];
    const int*   src   = (const int*)d_in[15];
    const int*   dst   = (const int*)d_in[16];

    const int N = in_sizes[0] / 128;
    const int E = in_sizes[15];
    float* out = (float*)d_out;

    // workspace carve
    float* q_buf        = (float*)d_ws;                      // N*128 f32
    unsigned short* pb  = (unsigned short*)(q_buf + (size_t)N * 128);  // N*128 bf16
    unsigned short* Mhi = pb + (size_t)N * 128;
    unsigned short* Mlo = Mhi + (size_t)N * 128;
    unsigned short* P0  = Mlo + (size_t)N * 128;
    unsigned short* Pq1 = P0  + 128 * 128 * 2;
    unsigned short* Pp1 = Pq1 + 128 * 128 * 2;
    unsigned short* Pq2 = Pp1 + 128 * 128 * 2;
    unsigned short* Pp2 = Pq2 + 128 * 64 * 2;
    int* offs    = (int*)(Pp2 + 128 * 64 * 2);
    int* csr_src = offs + (N + 2);
    const int CB = (N + 15) / 16;          // coarse bins (<= 4096 for N<=65536)
    const int M  = CB * 64;
    int* gh    = csr_src + E;
    int* gscan = gh + M;
    int* bsum  = gscan + M;                // 1024 ints
    // pairs aliases q_buf (dead until gemm layer-1); int2-aligned (base of ws)
    int2* pairs = (int2*)q_buf;

    const int NB1 = (M + 255) / 256;       // <= 1024

    // 1) weight prepack
    pack_w<<<dim3(64, 5), 256, 0, stream>>>(W0, Wq1, Wp1, Wq2, Wp2,
                                            P0, Pq1, Pp1, Pq2, Pp2);
    // 2-7) CSR build (atomic-free two-level counting sort)
    hist_coarse<<<64, 256, 0, stream>>>(dst, gh, E, CB);
    scan1_kernel<<<NB1, 256, 0, stream>>>(gh, gscan, bsum, M);
    scan2_kernel<<<1, 1024, 0, stream>>>(bsum, NB1);
    scan3_kernel<<<NB1, 256, 0, stream>>>(gscan, bsum, M);
    scatter_coarse<<<64, 256, 0, stream>>>(src, dst, gscan, pairs, E, CB);
    finalize_kernel<<<(CB + 3) / 4, 256, 0, stream>>>(pairs, gscan, offs, csr_src, N, E, CB);

    const int GB64 = (N + 63) / 64;
    const int GGAT = (N + 15) / 16;

    // 8) layer 0: m1 = gelu(x@W0 + b0) -> Mhi/Mlo
    mfma_gemm<128, false, 0><<<GB64, 256, 0, stream>>>(
        x, nullptr, nullptr, P0, b0, nullptr, nullptr,
        nullptr, nullptr, Mhi, Mlo, N);
    // 9) layer 1 projections: q1 fp32 + p1 bf16 in ONE pass over A
    mfma_gemm<128, true, 1><<<GB64, 256, 0, stream>>>(
        nullptr, Mhi, Mlo, Pq1, bq1, Pp1, bp1,
        q_buf, pb, nullptr, nullptr, N);
    // 10) layer 1 GAT -> m2 = gelu(h1 + bg2) -> Mhi/Mlo
    gat_agg<128, 0><<<GGAT, 256, 0, stream>>>(
        q_buf, pb, a1, bg2, offs, csr_src,
        nullptr, Mhi, Mlo, N);
    // 11) layer 2 projections: q2 fp32 + p2 bf16 in ONE pass over A
    mfma_gemm<64, true, 1><<<GB64, 256, 0, stream>>>(
        nullptr, Mhi, Mlo, Pq2, bq2, Pp2, bp2,
        q_buf, pb, nullptr, nullptr, N);
    // 12) layer 2 GAT + b_out -> d_out
    gat_agg<64, 1><<<GGAT, 256, 0, stream>>>(
        q_buf, pb, a2, b_out, offs, csr_src,
        out, nullptr, nullptr, N);
}

// Round 6
// 283.585 us; speedup vs baseline: 1.6452x; 1.0246x over previous
//
#include <hip/hip_runtime.h>
#include <hip/hip_bf16.h>
#include <math.h>

// GAT 2-layer fused pipeline for MI355X (gfx950).
// Round-15: gat_agg p-row gathers software-pipelined one batch ahead.
// r14 post-mortem: VALUBusy 60% = gather latency (300-600cy) serialized
// with ~400cy compute per iteration. Now: batch i+1's 4 gathers are issued
// at the TOP of iteration i (raw uint4 regs, unpack-on-compute), csr
// indices prefetched 2 batches ahead; the vmcnt wait for batch i+1 lands
// after batch i's compute. Idle-slot gathers clamp to csr_src[0] (hot
// line, near-free). Arithmetic order unchanged -> bit-identical output.
// GEMM (64-row single-pass-A), CSR build, ballot finalize unchanged (r14).

#define SLOPE 0.2f

typedef __attribute__((ext_vector_type(8))) __bf16 bf16x8;
typedef __attribute__((ext_vector_type(4))) float f32x4;

__device__ __forceinline__ float gelu_erf(float x) {
    return 0.5f * x * (1.0f + erff(x * 0.70710678118654752f));
}

__device__ __forceinline__ unsigned short f2bf(float f) {  // RNE
    unsigned int u = __float_as_uint(f);
    return (unsigned short)((u + 0x7fffu + ((u >> 16) & 1u)) >> 16);
}
__device__ __forceinline__ float bf2f(unsigned short h) {
    return __uint_as_float((unsigned int)h << 16);
}

// 16-lane (row) all-reduce sum via DPP row_ror 1,2,4,8; every lane of the
// row ends with the row's sum. Chains over different inputs are independent.
__device__ __forceinline__ float row16_sum(float x) {
    x += __int_as_float(__builtin_amdgcn_update_dpp(0, __float_as_int(x), 0x121, 0xF, 0xF, true));
    x += __int_as_float(__builtin_amdgcn_update_dpp(0, __float_as_int(x), 0x122, 0xF, 0xF, true));
    x += __int_as_float(__builtin_amdgcn_update_dpp(0, __float_as_int(x), 0x124, 0xF, 0xF, true));
    x += __int_as_float(__builtin_amdgcn_update_dpp(0, __float_as_int(x), 0x128, 0xF, 0xF, true));
    return x;
}

// XOR swizzle for LDS planes with 256B row stride: spreads the 16-row
// column slice of a ds_read_b128 across 8 distinct 16B slots.
__device__ __forceinline__ int swz(int off) { return off ^ ((off >> 4) & 0x70); }

// ---------------- weight prepack ---------------------------------------------
// Pack index i = ((ct*4+ks)*64 + lane)*8 + j  ->  W[k][n],
// k = ks*32 + (lane>>4)*8 + j,  n = ct*16 + (lane&15).  hi at [i], lo at [CE+i].
__global__ __launch_bounds__(256) void pack_w(
    const float* __restrict__ W0,  const float* __restrict__ Wq1,
    const float* __restrict__ Wp1, const float* __restrict__ Wq2,
    const float* __restrict__ Wp2,
    unsigned short* __restrict__ P0,  unsigned short* __restrict__ Pq1,
    unsigned short* __restrict__ Pp1, unsigned short* __restrict__ Pq2,
    unsigned short* __restrict__ Pp2)
{
    const float* W; unsigned short* P; int C;
    switch (blockIdx.y) {
        case 0:  W = W0;  P = P0;  C = 128; break;
        case 1:  W = Wq1; P = Pq1; C = 128; break;
        case 2:  W = Wp1; P = Pp1; C = 128; break;
        case 3:  W = Wq2; P = Pq2; C = 64;  break;
        default: W = Wp2; P = Pp2; C = 64;  break;
    }
    int i = blockIdx.x * 256 + threadIdx.x;
    int CE = C * 128;
    if (i >= CE) return;
    int j = i & 7, l = (i >> 3) & 63, ks = (i >> 9) & 3, ct = i >> 11;
    int k = ks * 32 + ((l >> 4) << 3) + j;
    int n = ct * 16 + (l & 15);
    float v = W[k * C + n];
    unsigned short hb = f2bf(v);
    P[i] = hb;
    P[CE + i] = f2bf(v - bf2f(hb));
}

// ---------------- MFMA GEMM -------------------------------------------------
// Block = 64 rows x ALL output cols; 4 waves split the col-tiles.
// A panel (64x128, hi+lo bf16 = 32 KB) staged in LDS once (swizzled);
// W fragments streamed from packed global (L2-resident).
// EPI 0: single matrix, out = gelu -> o1hi/o1lo (layer 0, A = fp32).
// EPI 1: TWO matrices: waves 0-1 -> q fp32 (direct), waves 2-3 -> p bf16
//        (LDS-bounced for coalesced 16B stores).
template <int C, bool TWO, int EPI>
__global__ __launch_bounds__(256) void mfma_gemm(
    const float* __restrict__ Af,
    const unsigned short* __restrict__ AHg, const unsigned short* __restrict__ ALg,
    const unsigned short* __restrict__ P1, const float* __restrict__ b1,
    const unsigned short* __restrict__ P2, const float* __restrict__ b2,
    float* __restrict__ outq, unsigned short* __restrict__ outp,
    unsigned short* __restrict__ o1hi, unsigned short* __restrict__ o1lo,
    int N)
{
    constexpr int CE  = C * 128;
    constexpr int CTT = (TWO ? 2 : 1) * (C / 16);   // total col-tiles
    constexpr int CTW = CTT / 4;                    // tiles per wave
    constexpr int QCT = C / 16;                     // tiles in first matrix

    __shared__ __align__(16) unsigned char lds[32768]; // hi plane [0,16K), lo [16K,32K)

    const int t = threadIdx.x;
    const int lane = t & 63;
    const int w = t >> 6;
    const int row0 = blockIdx.x * 64;
    const int mcol = lane & 15;
    const int hk = lane >> 4;

    // ---- stage A (64 rows x 128 dims) as hi/lo bf16 into LDS ----
    if constexpr (EPI == 0) {
#pragma unroll
        for (int i = 0; i < 8; i++) {
            int idx = t + i * 256;            // float4 index, 2048 total
            int row = idx >> 5;               // 32 float4 per row
            int gr = row0 + row;
            float4 v = make_float4(0.f, 0.f, 0.f, 0.f);
            if (gr < N) v = *reinterpret_cast<const float4*>(Af + (size_t)gr * 128 + (idx & 31) * 4);
            const float* f = reinterpret_cast<const float*>(&v);
            unsigned int h[4], l[4];
#pragma unroll
            for (int j = 0; j < 4; j++) {
                unsigned short hb = f2bf(f[j]);
                h[j] = hb;
                l[j] = f2bf(f[j] - bf2f(hb));
            }
            int so = swz(row * 256 + (idx & 31) * 8);
            *reinterpret_cast<uint2*>(&lds[so])         = make_uint2(h[0] | (h[1] << 16), h[2] | (h[3] << 16));
            *reinterpret_cast<uint2*>(&lds[16384 + so]) = make_uint2(l[0] | (l[1] << 16), l[2] | (l[3] << 16));
        }
    } else {
#pragma unroll
        for (int i = 0; i < 4; i++) {
            int idx = t + i * 256;            // uint4 index, 1024 per plane
            int row = idx >> 4;               // 16 uint4 per row
            int gr = row0 + row;
            uint4 vh = make_uint4(0, 0, 0, 0), vl = make_uint4(0, 0, 0, 0);
            if (gr < N) {
                vh = *reinterpret_cast<const uint4*>(AHg + (size_t)gr * 128 + (idx & 15) * 8);
                vl = *reinterpret_cast<const uint4*>(ALg + (size_t)gr * 128 + (idx & 15) * 8);
            }
            int so = swz(row * 256 + (idx & 15) * 16);
            *reinterpret_cast<uint4*>(&lds[so])         = vh;
            *reinterpret_cast<uint4*>(&lds[16384 + so]) = vl;
        }
    }
    __syncthreads();

    f32x4 acc[CTW][4];
#pragma unroll
    for (int c = 0; c < CTW; c++)
#pragma unroll
        for (int rf = 0; rf < 4; rf++) acc[c][rf] = (f32x4){0.f, 0.f, 0.f, 0.f};

#pragma unroll
    for (int ks = 0; ks < 4; ks++) {
        bf16x8 ah[4], al[4];
#pragma unroll
        for (int rf = 0; rf < 4; rf++) {
            int so = swz((rf * 16 + mcol) * 256 + ks * 64 + hk * 16);
            ah[rf] = *reinterpret_cast<const bf16x8*>(&lds[so]);
            al[rf] = *reinterpret_cast<const bf16x8*>(&lds[16384 + so]);
        }
#pragma unroll
        for (int c = 0; c < CTW; c++) {
            int ctg = w * CTW + c;
            bool isq = (!TWO) || (ctg < QCT);
            int ct = isq ? ctg : ctg - QCT;
            const unsigned short* P = isq ? P1 : P2;
            const unsigned short* Wp = P + ((ct * 4 + ks) * 64 + lane) * 8;
            bf16x8 bh = *reinterpret_cast<const bf16x8*>(Wp);
            bf16x8 bl = *reinterpret_cast<const bf16x8*>(Wp + CE);
#pragma unroll
            for (int rf = 0; rf < 4; rf++) {
                acc[c][rf] = __builtin_amdgcn_mfma_f32_16x16x32_bf16(ah[rf], bh, acc[c][rf], 0, 0, 0);
                acc[c][rf] = __builtin_amdgcn_mfma_f32_16x16x32_bf16(al[rf], bh, acc[c][rf], 0, 0, 0);
                acc[c][rf] = __builtin_amdgcn_mfma_f32_16x16x32_bf16(ah[rf], bl, acc[c][rf], 0, 0, 0);
            }
        }
    }

    __syncthreads();   // all A ds_reads done; LDS reused for epilogue staging

    // epilogue: C/D layout col=lane&15, row=(lane>>4)*4+reg
    if constexpr (EPI == 0) {
#pragma unroll
        for (int c = 0; c < CTW; c++) {
            int col = (w * CTW + c) * 16 + mcol;
            float bv = b1[col];
#pragma unroll
            for (int rf = 0; rf < 4; rf++) {
#pragma unroll
                for (int r = 0; r < 4; r++) {
                    int row = rf * 16 + hk * 4 + r;
                    float v = gelu_erf(acc[c][rf][r] + bv);
                    unsigned short hb = f2bf(v);
                    int bo = row * 256 + col * 2;
                    *reinterpret_cast<unsigned short*>(&lds[swz(bo)])         = hb;
                    *reinterpret_cast<unsigned short*>(&lds[16384 + swz(bo)]) = f2bf(v - bf2f(hb));
                }
            }
        }
        __syncthreads();
#pragma unroll
        for (int i = 0; i < 8; i++) {
            int idx = t + i * 256;          // 2048 uint4: hi 0..1023, lo 1024..2047
            int pl = idx >> 10;
            int j = idx & 1023;
            int row = j >> 4;
            int gr = row0 + row;
            if (gr < N) {
                uint4 v = *reinterpret_cast<const uint4*>(&lds[pl * 16384 + swz(row * 256 + (j & 15) * 16)]);
                unsigned short* dp = pl ? o1lo : o1hi;
                *reinterpret_cast<uint4*>(dp + (size_t)gr * 128 + (j & 15) * 8) = v;
            }
        }
    } else {
#pragma unroll
        for (int c = 0; c < CTW; c++) {
            int ctg = w * CTW + c;
            bool isq = ctg < QCT;
            int ct = isq ? ctg : ctg - QCT;
            int col = ct * 16 + mcol;
            float bv = (isq ? b1 : b2)[col];
#pragma unroll
            for (int rf = 0; rf < 4; rf++) {
#pragma unroll
                for (int r = 0; r < 4; r++) {
                    int row = rf * 16 + hk * 4 + r;
                    int gr = row0 + row;
                    float v = acc[c][rf][r] + bv;
                    if (isq) {
                        if (gr < N) outq[(size_t)gr * C + col] = v;   // 4B x 16 lanes = full line
                    } else {
                        *reinterpret_cast<unsigned short*>(&lds[swz(row * 256 + col * 2)]) = f2bf(v);
                    }
                }
            }
        }
        __syncthreads();
        constexpr int SLOTS = C / 8;        // uint4 slots per row (16 or 8)
#pragma unroll
        for (int i = 0; i < (64 * SLOTS) / 256; i++) {
            int idx = t + i * 256;
            int row = idx / SLOTS;
            int sl = idx % SLOTS;
            int gr = row0 + row;
            if (gr < N)
                *reinterpret_cast<uint4*>(outp + (size_t)gr * C + sl * 8) =
                    *reinterpret_cast<const uint4*>(&lds[swz(row * 256 + sl * 16)]);
        }
    }
}

// ---------------- CSR build: atomic-free two-level counting sort -------------
// Coarse bin = dst >> 4 (16 nodes per bin), CB = ceil(N/16) <= 4096.
// 64 edge-blocks; gh[bin*64 + blk] = count (bin-major for linear scan).

__global__ __launch_bounds__(256) void hist_coarse(
    const int* __restrict__ dst, int* __restrict__ gh, int E, int CB)
{
    __shared__ int cnt[4096];
    const int blk = blockIdx.x;     // 0..63
    const int t = threadIdx.x;
    for (int b = t; b < CB; b += 256) cnt[b] = 0;
    __syncthreads();
    const int epb = (E + 63) / 64;
    const int s = blk * epb;
    const int e_ = (s + epb < E) ? s + epb : E;
    for (int i = s + t; i < e_; i += 256)
        atomicAdd(&cnt[dst[i] >> 4], 1);
    __syncthreads();
    for (int b = t; b < CB; b += 256)
        gh[b * 64 + blk] = cnt[b];
}

// hierarchical exclusive scan over M = CB*64 values: gh -> gscan
__global__ __launch_bounds__(256) void scan1_kernel(const int* __restrict__ gh,
                                                    int* __restrict__ gscan,
                                                    int* __restrict__ bsum, int M)
{
    __shared__ int lds[256];
    int t = threadIdx.x;
    int i = blockIdx.x * 256 + t;
    int v = (i < M) ? gh[i] : 0;
    lds[t] = v;
    __syncthreads();
    int x = v;
    for (int off = 1; off < 256; off <<= 1) {
        int y = (t >= off) ? lds[t - off] : 0;
        __syncthreads();
        x += y;
        lds[t] = x;
        __syncthreads();
    }
    if (i < M) gscan[i] = x - v;
    if (t == 255) bsum[blockIdx.x] = x;
}

__global__ __launch_bounds__(1024) void scan2_kernel(int* __restrict__ bsum, int NB)
{
    __shared__ int lds[1024];
    int t = threadIdx.x;
    int v = (t < NB) ? bsum[t] : 0;
    lds[t] = v;
    __syncthreads();
    int x = v;
    for (int off = 1; off < 1024; off <<= 1) {
        int y = (t >= off) ? lds[t - off] : 0;
        __syncthreads();
        x += y;
        lds[t] = x;
        __syncthreads();
    }
    if (t < NB) bsum[t] = x - v;
}

__global__ __launch_bounds__(256) void scan3_kernel(int* __restrict__ gscan,
                                                    const int* __restrict__ bsum, int M)
{
    int i = blockIdx.x * 256 + threadIdx.x;
    if (i < M) gscan[i] += bsum[blockIdx.x];
}

// scatter edges into coarse-bin-grouped (dst,src) pairs; LDS cursors only.
__global__ __launch_bounds__(256) void scatter_coarse(
    const int* __restrict__ src, const int* __restrict__ dst,
    const int* __restrict__ gscan, int2* __restrict__ pairs, int E, int CB)
{
    __shared__ int cur[4096];
    const int blk = blockIdx.x;     // 0..63
    const int t = threadIdx.x;
    for (int b = t; b < CB; b += 256)
        cur[b] = gscan[b * 64 + blk];
    __syncthreads();
    const int epb = (E + 63) / 64;
    const int s = blk * epb;
    const int e_ = (s + epb < E) ? s + epb : E;
    for (int i = s + t; i < e_; i += 256) {
        int d = dst[i];
        int sv = src[i];
        int pos = atomicAdd(&cur[d >> 4], 1);   // LDS atomic
        pairs[pos] = make_int2(d, sv);
    }
}

// one WAVE per coarse bin: ballot-histogram counts, exclusive scan, stable
// ranks via popcount(ballot & lanemask_lt) + per-chunk running cursor in
// lane j (fetched per-lane with one ds_bpermute). Zero LDS, zero atomics.
__global__ __launch_bounds__(256) void finalize_kernel(
    const int2* __restrict__ pairs, const int* __restrict__ gscan,
    int* __restrict__ offs, int* __restrict__ csr_src, int N, int E, int CB)
{
    const int wid = blockIdx.x * 4 + (threadIdx.x >> 6);   // bin index
    const int lane = threadIdx.x & 63;
    if (wid >= CB) return;                                 // wave-uniform exit

    const int s    = gscan[wid * 64];
    const int e_   = (wid + 1 < CB) ? gscan[(wid + 1) * 64] : E;
    const int base = wid * 16;
    const unsigned long long ltmask = (lane == 63) ? ~0ull >> 1
                                                   : (1ull << lane) - 1ull;

    // pass 1: per-node counts via ballot histogram (rc[j] wave-uniform)
    int rc[16];
#pragma unroll
    for (int j = 0; j < 16; j++) rc[j] = 0;
    for (int c0 = s; c0 < e_; c0 += 64) {
        int i = c0 + lane;
        int d = (i < e_) ? pairs[i].x - base : -1;
#pragma unroll
        for (int j = 0; j < 16; j++)
            rc[j] += (int)__popcll(__ballot(d == j));
    }

    // exclusive scan -> pref[]; vector copy in lane j for bpermute lookups
    int pref[16];
    int run = s;
#pragma unroll
    for (int j = 0; j < 16; j++) { pref[j] = run; run += rc[j]; }
    int pref_v = 0;
#pragma unroll
    for (int j = 0; j < 16; j++) pref_v = (lane == j) ? pref[j] : pref_v;

    if (lane < 16 && base + lane < N) offs[base + lane] = pref_v;
    if (wid == CB - 1 && lane == 16) offs[N] = E;

    // pass 2: stable rank + contiguous scatter
    int rcv = 0;                       // lane j holds running count of node j
    for (int c0 = s; c0 < e_; c0 += 64) {
        int i = c0 + lane;
        const bool act = i < e_;
        int2 pr = act ? pairs[i] : make_int2(base - 1, 0);
        int d = pr.x - base;           // -1 for inactive lanes
        unsigned long long msel = 0;
        int addcnt = 0;
#pragma unroll
        for (int j = 0; j < 16; j++) {
            unsigned long long m = __ballot(d == j);
            if (d == j) msel = m;
            if (lane == j) addcnt = (int)__popcll(m);
        }
        int subrank = (int)__popcll(msel & ltmask);
        int posbase = __builtin_amdgcn_ds_bpermute(d * 4, pref_v + rcv);
        if (act) csr_src[posbase + subrank] = pr.y;
        rcv += addcnt;
    }
}

// ---------------- fused GAT edge-softmax + aggregation -----------------------
// 16 lanes per dst node, 4 nodes per wave, 4 edges per group-iteration.
// Software-pipelined: batch i+1's p-row gathers are issued at the top of
// iteration i (kept as raw uint4/uint2 in regs; unpack happens during
// compute), csr indices prefetched 2 batches ahead. The vmcnt wait for
// batch i+1 lands after batch i's ~400cy compute -> gather latency hidden.
// Score partial per edge = fma(d,0.6a)+fma(|d|,0.4a); 4 independent DPP
// row_ror reduce chains; inactive slots masked branchlessly.
// EPI 0 (D=128): m2 = gelu(h+bvec) packed hi/lo bf16.  EPI 1 (D=64): fp32 out.
template <int D, int EPI>
__global__ __launch_bounds__(256) void gat_agg(
    const float* __restrict__ q, const unsigned short* __restrict__ p,
    const float* __restrict__ a, const float* __restrict__ bvec,
    const int* __restrict__ offs, const int* __restrict__ csr_src,
    float* __restrict__ out, unsigned short* __restrict__ mhi,
    unsigned short* __restrict__ mlo, int N)
{
    constexpr int VPL = D / 16;   // dims per lane: 8 (D=128) or 4 (D=64)
    const int t = threadIdx.x;
    const int lane = t & 63;
    const int sl = lane & 15;
    const int base = sl * VPL;
    const int node = blockIdx.x * 16 + ((t >> 6) << 2) + (lane >> 4);
    const bool valid = node < N;

    float qv[VPL], a6[VPL], a4[VPL], acc[VPL];
#pragma unroll
    for (int v = 0; v < VPL; v++) { qv[v] = 0.f; acc[v] = 0.f; }
    if (valid) {
        const float* qp = q + (size_t)node * D + base;
        float4 q0 = *reinterpret_cast<const float4*>(qp);
        qv[0] = q0.x; qv[1] = q0.y; qv[2] = q0.z; qv[3] = q0.w;
        if constexpr (VPL == 8) {
            float4 q1 = *reinterpret_cast<const float4*>(qp + 4);
            qv[4] = q1.x; qv[5] = q1.y; qv[6] = q1.z; qv[7] = q1.w;
        }
    }
#pragma unroll
    for (int v = 0; v < VPL; v++) {
        float av = a[base + v];
        a6[v] = 0.6f * av;
        a4[v] = 0.4f * av;
    }

    // raw-row gather (per-lane 16B / 8B slice of the 16-lane row)
    auto gather = [&](int s) -> uint4 {
        if constexpr (D == 128) {
            return *reinterpret_cast<const uint4*>(p + (size_t)s * 128 + base);
        } else {
            uint2 u = *reinterpret_cast<const uint2*>(p + (size_t)s * 64 + base);
            return make_uint4(u.x, u.y, 0u, 0u);
        }
    };
    auto unpack = [&](uint4 u, float* pv) {
        pv[0] = __uint_as_float(u.x << 16); pv[1] = __uint_as_float(u.x & 0xffff0000u);
        pv[2] = __uint_as_float(u.y << 16); pv[3] = __uint_as_float(u.y & 0xffff0000u);
        if constexpr (VPL == 8) {
            pv[4] = __uint_as_float(u.z << 16); pv[5] = __uint_as_float(u.z & 0xffff0000u);
            pv[6] = __uint_as_float(u.w << 16); pv[7] = __uint_as_float(u.w & 0xffff0000u);
        }
    };

    float denom = 0.f;
    int e  = valid ? offs[node] : 0;
    int e1 = valid ? offs[node + 1] : 0;

    // prologue: batch-0 indices + gathers; batch-1 indices
    int s0 = csr_src[(e + 0 < e1) ? e + 0 : 0];
    int s1 = csr_src[(e + 1 < e1) ? e + 1 : 0];
    int s2 = csr_src[(e + 2 < e1) ? e + 2 : 0];
    int s3 = csr_src[(e + 3 < e1) ? e + 3 : 0];
    uint4 uA0 = gather(s0), uA1 = gather(s1), uA2 = gather(s2), uA3 = gather(s3);
    int en = e + 4;
    int n0 = csr_src[(en + 0 < e1) ? en + 0 : 0];
    int n1 = csr_src[(en + 1 < e1) ? en + 1 : 0];
    int n2 = csr_src[(en + 2 < e1) ? en + 2 : 0];
    int n3 = csr_src[(en + 3 < e1) ? en + 3 : 0];

    while (__any(e < e1)) {
        const bool a0 = (e + 0) < e1, a1b = (e + 1) < e1,
                   a2 = (e + 2) < e1, a3 = (e + 3) < e1;

        // issue NEXT batch's gathers (latency hides under this batch's compute)
        uint4 v0 = gather(n0), v1 = gather(n1), v2 = gather(n2), v3 = gather(n3);

        // prefetch batch+2 csr indices
        const int em = en + 4;
        const int m0 = csr_src[(em + 0 < e1) ? em + 0 : 0];
        const int m1 = csr_src[(em + 1 < e1) ? em + 1 : 0];
        const int m2 = csr_src[(em + 2 < e1) ? em + 2 : 0];
        const int m3 = csr_src[(em + 3 < e1) ? em + 3 : 0];

        // compute on current batch (uA*, already resident)
        float pv[4][VPL];
        unpack(uA0, pv[0]); unpack(uA1, pv[1]); unpack(uA2, pv[2]); unpack(uA3, pv[3]);

        float pa0 = 0.f, pa1 = 0.f, pa2 = 0.f, pa3 = 0.f;
#pragma unroll
        for (int v = 0; v < VPL; v++) {
            float d0 = qv[v] + pv[0][v];
            float d1 = qv[v] + pv[1][v];
            float d2 = qv[v] + pv[2][v];
            float d3 = qv[v] + pv[3][v];
            pa0 = fmaf(d0, a6[v], pa0); pa0 = fmaf(fabsf(d0), a4[v], pa0);
            pa1 = fmaf(d1, a6[v], pa1); pa1 = fmaf(fabsf(d1), a4[v], pa1);
            pa2 = fmaf(d2, a6[v], pa2); pa2 = fmaf(fabsf(d2), a4[v], pa2);
            pa3 = fmaf(d3, a6[v], pa3); pa3 = fmaf(fabsf(d3), a4[v], pa3);
        }

        float r0 = row16_sum(pa0);
        float r1 = row16_sum(pa1);
        float r2 = row16_sum(pa2);
        float r3 = row16_sum(pa3);

        float esm0 = a0  ? __expf(r0) : 0.f;
        float esm1 = a1b ? __expf(r1) : 0.f;
        float esm2 = a2  ? __expf(r2) : 0.f;
        float esm3 = a3  ? __expf(r3) : 0.f;
        denom += (esm0 + esm1) + (esm2 + esm3);
#pragma unroll
        for (int v = 0; v < VPL; v++) {
            acc[v] = fmaf(esm0, pv[0][v], acc[v]);
            acc[v] = fmaf(esm1, pv[1][v], acc[v]);
            acc[v] = fmaf(esm2, pv[2][v], acc[v]);
            acc[v] = fmaf(esm3, pv[3][v], acc[v]);
        }

        // rotate pipeline
        uA0 = v0; uA1 = v1; uA2 = v2; uA3 = v3;
        n0 = m0; n1 = m1; n2 = m2; n3 = m3;
        e = en; en = em;
    }

    if (!valid) return;
    float inv = (denom != 0.f) ? 1.f / denom : 0.f;  // zero-degree -> agg = 0
    if constexpr (EPI == 0) {
        union { unsigned short us[8]; uint4 v; } H, L;
#pragma unroll
        for (int v = 0; v < VPL; v++) {
            float g = gelu_erf(acc[v] * inv + bvec[base + v]);
            H.us[v] = f2bf(g);
            L.us[v] = f2bf(g - bf2f(H.us[v]));
        }
        *reinterpret_cast<uint4*>(mhi + (size_t)node * 128 + base) = H.v;
        *reinterpret_cast<uint4*>(mlo + (size_t)node * 128 + base) = L.v;
    } else {
        union { float f[4]; float4 v; } O;
#pragma unroll
        for (int v = 0; v < VPL; v++) O.f[v] = acc[v] * inv + bvec[base + v];
        *reinterpret_cast<float4*>(out + (size_t)node * D + base) = O.v;
    }
}

// ---------------- launch ------------------------------------------------------
extern "C" void kernel_launch(void* const* d_in, const int* in_sizes, int n_in,
                              void* d_out, int out_size, void* d_ws, size_t ws_size,
                              hipStream_t stream)
{
    const float* x     = (const float*)d_in[0];
    const float* W0    = (const float*)d_in[1];
    const float* b0    = (const float*)d_in[2];
    const float* Wq1   = (const float*)d_in[3];
    const float* bq1   = (const float*)d_in[4];
    const float* Wp1   = (const float*)d_in[5];
    const float* bp1   = (const float*)d_in[6];
    const float* a1    = (const float*)d_in[7];
    const float* bg2   = (const float*)d_in[8];
    const float* Wq2   = (const float*)d_in[9];
    const float* bq2   = (const float*)d_in[10];
    const float* Wp2   = (const float*)d_in[11];
    const float* bp2   = (const float*)d_in[12];
    const float* a2    = (const float*)d_in[13];
    const float* b_out = (const float*)d_in[14];
    const int*   src   = (const int*)d_in[15];
    const int*   dst   = (const int*)d_in[16];

    const int N = in_sizes[0] / 128;
    const int E = in_sizes[15];
    float* out = (float*)d_out;

    // workspace carve
    float* q_buf        = (float*)d_ws;                      // N*128 f32
    unsigned short* pb  = (unsigned short*)(q_buf + (size_t)N * 128);  // N*128 bf16
    unsigned short* Mhi = pb + (size_t)N * 128;
    unsigned short* Mlo = Mhi + (size_t)N * 128;
    unsigned short* P0  = Mlo + (size_t)N * 128;
    unsigned short* Pq1 = P0  + 128 * 128 * 2;
    unsigned short* Pp1 = Pq1 + 128 * 128 * 2;
    unsigned short* Pq2 = Pp1 + 128 * 128 * 2;
    unsigned short* Pp2 = Pq2 + 128 * 64 * 2;
    int* offs    = (int*)(Pp2 + 128 * 64 * 2);
    int* csr_src = offs + (N + 2);
    const int CB = (N + 15) / 16;          // coarse bins (<= 4096 for N<=65536)
    const int M  = CB * 64;
    int* gh    = csr_src + E;
    int* gscan = gh + M;
    int* bsum  = gscan + M;                // 1024 ints
    // pairs aliases q_buf (dead until gemm layer-1); int2-aligned (base of ws)
    int2* pairs = (int2*)q_buf;

    const int NB1 = (M + 255) / 256;       // <= 1024

    // 1) weight prepack
    pack_w<<<dim3(64, 5), 256, 0, stream>>>(W0, Wq1, Wp1, Wq2, Wp2,
                                            P0, Pq1, Pp1, Pq2, Pp2);
    // 2-7) CSR build (atomic-free two-level counting sort)
    hist_coarse<<<64, 256, 0, stream>>>(dst, gh, E, CB);
    scan1_kernel<<<NB1, 256, 0, stream>>>(gh, gscan, bsum, M);
    scan2_kernel<<<1, 1024, 0, stream>>>(bsum, NB1);
    scan3_kernel<<<NB1, 256, 0, stream>>>(gscan, bsum, M);
    scatter_coarse<<<64, 256, 0, stream>>>(src, dst, gscan, pairs, E, CB);
    finalize_kernel<<<(CB + 3) / 4, 256, 0, stream>>>(pairs, gscan, offs, csr_src, N, E, CB);

    const int GB64 = (N + 63) / 64;
    const int GGAT = (N + 15) / 16;

    // 8) layer 0: m1 = gelu(x@W0 + b0) -> Mhi/Mlo
    mfma_gemm<128, false, 0><<<GB64, 256, 0, stream>>>(
        x, nullptr, nullptr, P0, b0, nullptr, nullptr,
        nullptr, nullptr, Mhi, Mlo, N);
    // 9) layer 1 projections: q1 fp32 + p1 bf16 in ONE pass over A
    mfma_gemm<128, true, 1><<<GB64, 256, 0, stream>>>(
        nullptr, Mhi, Mlo, Pq1, bq1, Pp1, bp1,
        q_buf, pb, nullptr, nullptr, N);
    // 10) layer 1 GAT -> m2 = gelu(h1 + bg2) -> Mhi/Mlo
    gat_agg<128, 0><<<GGAT, 256, 0, stream>>>(
        q_buf, pb, a1, bg2, offs, csr_src,
        nullptr, Mhi, Mlo, N);
    // 11) layer 2 projections: q2 fp32 + p2 bf16 in ONE pass over A
    mfma_gemm<64, true, 1><<<GB64, 256, 0, stream>>>(
        nullptr, Mhi, Mlo, Pq2, bq2, Pp2, bp2,
        q_buf, pb, nullptr, nullptr, N);
    // 12) layer 2 GAT + b_out -> d_out
    gat_agg<64, 1><<<GGAT, 256, 0, stream>>>(
        q_buf, pb, a2, b_out, offs, csr_src,
        out, nullptr, nullptr, N);
}